// Round 2
// baseline (6049.977 us; speedup 1.0000x reference)
//
#include <hip/hip_runtime.h>
#include <hip/hip_bf16.h>

#define N_NODES 100000
#define T_STEPS 10
#define F_DIM   64
#define E_EDGES 1600000
#define ED_DIM  8
#define H_DIM   128
#define B_BATCH 2048
#define C_CLS   2
#define TF      640      // T*F
#define K_IN    136      // F (self) + F (agg-x) + ED (agg-edge)
#define G4H     512      // 4*H

// ---- workspace layout (offsets in floats) ----
#define WS_DEG      0            // N ints
#define WS_INV      100096       // N floats
#define WS_AGGE     200192       // N*8
#define WS_AGGX     1000192      // N*64
#define WS_SUMS     7400192      // 256 (sum[128], sumsq[128]) — adjacent to aggx for one memset
#define WS_SCSH     7400448      // 256 (scale[128], shift[128])
#define WS_HSEQ     7400704      // T*B*H = 2621440
#define WS_H        10022144     // B*H
#define WS_C        10284288     // B*H  (adjacent to WS_H for one memset)
#define WS_WIT      10546432     // 128*512
#define WS_WHT      10611968     // 128*512

// ---------------- degree / inverse count ----------------
__global__ void k_deg(const int* __restrict__ ei, int* __restrict__ deg) {
    int e = blockIdx.x * blockDim.x + threadIdx.x;
    if (e < E_EDGES) atomicAdd(&deg[ei[E_EDGES + e]], 1);
}

__global__ void k_inv(const int* __restrict__ deg, float* __restrict__ inv) {
    int n = blockIdx.x * blockDim.x + threadIdx.x;
    if (n < N_NODES) { int d = deg[n]; inv[n] = 1.0f / (float)(d > 1 ? d : 1); }
}

// ---------------- edge-attr aggregation (t-invariant, once per call) ----------------
__global__ void k_agge(const int* __restrict__ ei, const float* __restrict__ ea,
                       float* __restrict__ agge) {
    int i = blockIdx.x * blockDim.x + threadIdx.x;   // over E*8
    if (i < E_EDGES * ED_DIM) {
        int e = i >> 3, j = i & 7;
        int dst = ei[E_EDGES + e];
        atomicAdd(&agge[dst * ED_DIM + j], ea[i]);
    }
}

// ---------------- LSTM weight pre-transpose (once per call) ----------------
__global__ void k_transpose(const float* __restrict__ wih, const float* __restrict__ whh,
                            float* __restrict__ wiT, float* __restrict__ whT) {
    int i = blockIdx.x * blockDim.x + threadIdx.x;   // over 512*128, output-centric
    if (i < G4H * H_DIM) {
        int k = i >> 9, j = i & 511;
        wiT[i] = wih[j * H_DIM + k];
        whT[i] = whh[j * H_DIM + k];
    }
}

// ---------------- per-t x scatter: aggx[dst] += x_t[src] ----------------
// one wave per edge: lane f handles feature f (coalesced 256B read + atomic region)
__global__ __launch_bounds__(256) void k_scatter(const float* __restrict__ x,
                                                 const int* __restrict__ ei,
                                                 float* __restrict__ aggx, int t) {
    int e    = blockIdx.x * 4 + (threadIdx.x >> 6);
    int lane = threadIdx.x & 63;
    int src = ei[e];
    int dst = ei[E_EDGES + e];
    float v = x[src * TF + t * F_DIM + lane];
    atomicAdd(&aggx[dst * F_DIM + lane], v);
}

// ---------------- BN stats: sum & sumsq of (xin @ W) over all N rows ----------------
// block = 256 threads, 32 rows; thread computes 4 rows x 4 cols register tile.
// K split into 2 chunks of 68 so the fp32 weight tile fits in LDS.
__global__ __launch_bounds__(256) void k_stats(const float* __restrict__ x,
        const float* __restrict__ aggx, const float* __restrict__ agge,
        const float* __restrict__ inv, const float* __restrict__ wself,
        const float* __restrict__ wmsg, float* __restrict__ sums, int t) {
    __shared__ float s_xin[32 * 137];
    __shared__ float s_w[68 * 128];
    __shared__ float s_sum[H_DIM], s_sq[H_DIM];
    int tid  = threadIdx.x;
    int row0 = blockIdx.x * 32;

    for (int idx = tid; idx < 32 * K_IN; idx += 256) {
        int r = idx / K_IN, k = idx - r * K_IN;
        int n = row0 + r;                       // N % 32 == 0, always valid
        float v;
        if (k < 64)       v = x[n * TF + t * F_DIM + k];
        else if (k < 128) v = aggx[n * F_DIM + (k - 64)] * inv[n];
        else              v = agge[n * ED_DIM + (k - 128)] * inv[n];
        s_xin[r * 137 + k] = v;
    }
    if (tid < H_DIM) { s_sum[tid] = 0.f; s_sq[tid] = 0.f; }

    int tx = tid & 31, ty = tid >> 5;           // cols tx*4+j, rows ty*4+i
    float acc[4][4];
    #pragma unroll
    for (int i = 0; i < 4; i++)
        #pragma unroll
        for (int j = 0; j < 4; j++) acc[i][j] = 0.f;

    for (int kc = 0; kc < 2; kc++) {
        __syncthreads();   // (kc=0) s_xin ready; (kc=1) all reads of previous s_w done
        for (int i = tid; i < 68 * 128; i += 256) {
            int gk = kc * 68 + (i >> 7), c = i & 127;
            s_w[i] = (gk < 64) ? wself[gk * 128 + c] : wmsg[(gk - 64) * 128 + c];
        }
        __syncthreads();
        const float4* s_w4 = (const float4*)s_w;
        for (int k2 = 0; k2 < 68; k2++) {
            float a[4];
            #pragma unroll
            for (int i = 0; i < 4; i++) a[i] = s_xin[(ty * 4 + i) * 137 + kc * 68 + k2];
            float4 b4 = s_w4[k2 * 32 + tx];
            #pragma unroll
            for (int i = 0; i < 4; i++) {
                acc[i][0] += a[i] * b4.x;
                acc[i][1] += a[i] * b4.y;
                acc[i][2] += a[i] * b4.z;
                acc[i][3] += a[i] * b4.w;
            }
        }
    }

    #pragma unroll
    for (int j = 0; j < 4; j++) {
        int h = tx * 4 + j;
        float cs = 0.f, cq = 0.f;
        #pragma unroll
        for (int i = 0; i < 4; i++) { cs += acc[i][j]; cq += acc[i][j] * acc[i][j]; }
        atomicAdd(&s_sum[h], cs);
        atomicAdd(&s_sq[h], cq);
    }
    __syncthreads();
    if (tid < H_DIM) {
        atomicAdd(&sums[tid], s_sum[tid]);
        atomicAdd(&sums[H_DIM + tid], s_sq[tid]);
    }
}

// ---------------- fold stats into scale/shift (biases are zero and cancel in BN) ----------------
__global__ void k_finalize(const float* __restrict__ sums, const float* __restrict__ gamma,
                           const float* __restrict__ beta, float* __restrict__ scsh) {
    int h = threadIdx.x;
    if (h < H_DIM) {
        float mean = sums[h] / (float)N_NODES;
        float var  = sums[H_DIM + h] / (float)N_NODES - mean * mean;
        var = fmaxf(var, 0.f);
        float istd = 1.0f / sqrtf(var + 1e-5f);
        float sc = gamma[h] * istd;
        scsh[h]         = sc;
        scsh[H_DIM + h] = beta[h] - mean * sc;
    }
}

// ---------------- focal rows: h_seq[t,b,:] = relu(BN(xin[ptr[b]] @ W)) ----------------
__global__ __launch_bounds__(128) void k_focal(const float* __restrict__ x,
        const float* __restrict__ aggx, const float* __restrict__ agge,
        const float* __restrict__ inv, const float* __restrict__ wself,
        const float* __restrict__ wmsg, const float* __restrict__ scsh,
        const int* __restrict__ ptr, float* __restrict__ hseq, int t) {
    __shared__ float s_xin[K_IN];
    int b   = blockIdx.x;
    int n   = ptr[b];
    int tid = threadIdx.x;
    for (int k = tid; k < K_IN; k += 128) {
        float v;
        if (k < 64)       v = x[n * TF + t * F_DIM + k];
        else if (k < 128) v = aggx[n * F_DIM + (k - 64)] * inv[n];
        else              v = agge[n * ED_DIM + (k - 128)] * inv[n];
        s_xin[k] = v;
    }
    __syncthreads();
    int h = tid;
    float acc = 0.f;
    #pragma unroll 8
    for (int k = 0; k < F_DIM; k++) acc += s_xin[k] * wself[k * H_DIM + h];
    #pragma unroll 8
    for (int k = 0; k < 72; k++)    acc += s_xin[F_DIM + k] * wmsg[k * H_DIM + h];
    float v = acc * scsh[h] + scsh[H_DIM + h];
    hseq[(t * B_BATCH + b) * H_DIM + h] = fmaxf(v, 0.f);
}

// ---------------- one fused LSTM step: gates GEMM + pointwise update ----------------
__global__ __launch_bounds__(512) void k_lstm(const float* __restrict__ hseq_t,
        const float* __restrict__ wiT, const float* __restrict__ whT,
        const float* __restrict__ bih, const float* __restrict__ bhh,
        float* __restrict__ h, float* __restrict__ c) {
    __shared__ float s_hin[16][H_DIM];
    __shared__ float s_hpr[16][H_DIM];
    __shared__ float s_g[16][G4H];
    int tid  = threadIdx.x;
    int row0 = blockIdx.x * 16;
    for (int idx = tid; idx < 16 * H_DIM; idx += 512) {
        int r = idx >> 7, k = idx & 127;
        s_hin[r][k] = hseq_t[(row0 + r) * H_DIM + k];
        s_hpr[r][k] = h[(row0 + r) * H_DIM + k];
    }
    __syncthreads();
    int j = tid;
    float acc[16];
    #pragma unroll
    for (int r = 0; r < 16; r++) acc[r] = 0.f;
    for (int k = 0; k < H_DIM; k++) {
        float wi = wiT[k * G4H + j];
        float wh = whT[k * G4H + j];
        #pragma unroll
        for (int r = 0; r < 16; r++) acc[r] += s_hin[r][k] * wi + s_hpr[r][k] * wh;
    }
    float bias = bih[j] + bhh[j];
    #pragma unroll
    for (int r = 0; r < 16; r++) s_g[r][j] = acc[r] + bias;
    __syncthreads();
    for (int m = tid; m < 16 * H_DIM; m += 512) {
        int r = m >> 7, hh = m & 127;
        float gi = s_g[r][hh];
        float gf = s_g[r][hh + 128];
        float gg = s_g[r][hh + 256];
        float go = s_g[r][hh + 384];
        float si = 1.f / (1.f + expf(-gi));
        float sf = 1.f / (1.f + expf(-gf));
        float so = 1.f / (1.f + expf(-go));
        float tg = tanhf(gg);
        int gidx = (row0 + r) * H_DIM + hh;
        float cn = sf * c[gidx] + si * tg;
        c[gidx] = cn;
        h[gidx] = so * tanhf(cn);
    }
}

// ---------------- classifier ----------------
__global__ void k_cls(const float* __restrict__ h, const float* __restrict__ wcls,
                      const float* __restrict__ bcls, float* __restrict__ out) {
    int i = blockIdx.x * blockDim.x + threadIdx.x;
    if (i < B_BATCH * C_CLS) {
        int b = i >> 1, cc = i & 1;
        float acc = bcls[cc];
        for (int k = 0; k < H_DIM; k++) acc += h[b * H_DIM + k] * wcls[k * C_CLS + cc];
        out[i] = acc;
    }
}

extern "C" void kernel_launch(void* const* d_in, const int* in_sizes, int n_in,
                              void* d_out, int out_size, void* d_ws, size_t ws_size,
                              hipStream_t stream) {
    const float* x     = (const float*)d_in[0];
    const int*   ei    = (const int*)d_in[1];
    const float* ea    = (const float*)d_in[2];
    const int*   ptr   = (const int*)d_in[3];
    const float* wmsg  = (const float*)d_in[4];
    const float* wself = (const float*)d_in[6];
    const float* gamma = (const float*)d_in[8];
    const float* beta  = (const float*)d_in[9];
    const float* wih   = (const float*)d_in[10];
    const float* whh   = (const float*)d_in[11];
    const float* bih   = (const float*)d_in[12];
    const float* bhh   = (const float*)d_in[13];
    const float* wcls  = (const float*)d_in[14];
    const float* bcls  = (const float*)d_in[15];
    float* out = (float*)d_out;

    float* ws   = (float*)d_ws;
    int*   deg  = (int*)(ws + WS_DEG);
    float* inv  = ws + WS_INV;
    float* agge = ws + WS_AGGE;
    float* aggx = ws + WS_AGGX;
    float* sums = ws + WS_SUMS;
    float* scsh = ws + WS_SCSH;
    float* hseq = ws + WS_HSEQ;
    float* hbuf = ws + WS_H;
    float* cbuf = ws + WS_C;
    float* wiT  = ws + WS_WIT;
    float* whT  = ws + WS_WHT;

    // zero: [deg, inv, agge] in one memset; [h, c] in one memset
    hipMemsetAsync(ws + WS_DEG, 0, (size_t)(WS_AGGX - WS_DEG) * 4, stream);
    hipMemsetAsync(ws + WS_H,   0, (size_t)(2 * B_BATCH * H_DIM) * 4, stream);

    k_deg<<<(E_EDGES + 255) / 256, 256, 0, stream>>>(ei, deg);
    k_inv<<<(N_NODES + 255) / 256, 256, 0, stream>>>(deg, inv);
    k_agge<<<(E_EDGES * ED_DIM + 255) / 256, 256, 0, stream>>>(ei, ea, agge);
    k_transpose<<<(G4H * H_DIM + 255) / 256, 256, 0, stream>>>(wih, whh, wiT, whT);

    for (int t = 0; t < T_STEPS; t++) {
        // zero aggx + sums (adjacent) in one memset
        hipMemsetAsync(aggx, 0, (size_t)(N_NODES * F_DIM + 256) * 4, stream);
        k_scatter<<<E_EDGES / 4, 256, 0, stream>>>(x, ei, aggx, t);
        k_stats<<<N_NODES / 32, 256, 0, stream>>>(x, aggx, agge, inv, wself, wmsg, sums, t);
        k_finalize<<<1, 128, 0, stream>>>(sums, gamma, beta, scsh);
        k_focal<<<B_BATCH, 128, 0, stream>>>(x, aggx, agge, inv, wself, wmsg, scsh, ptr, hseq, t);
    }
    for (int t = 0; t < T_STEPS; t++) {
        k_lstm<<<B_BATCH / 16, 512, 0, stream>>>(hseq + (size_t)t * B_BATCH * H_DIM,
                                                 wiT, whT, bih, bhh, hbuf, cbuf);
    }
    k_cls<<<(B_BATCH * C_CLS + 255) / 256, 256, 0, stream>>>(hbuf, wcls, bcls, out);
}

// Round 3
// 3236.020 us; speedup vs baseline: 1.8696x; 1.8696x over previous
//
#include <hip/hip_runtime.h>
#include <hip/hip_bf16.h>

#define N_NODES 100000
#define T_STEPS 10
#define F_DIM   64
#define E_EDGES 1600000
#define ED_DIM  8
#define H_DIM   128
#define B_BATCH 2048
#define C_CLS   2
#define TF      640      // T*F
#define K_IN    136      // F (self) + F (agg-x) + ED (agg-edge)
#define G4H     512      // 4*H

// ---- workspace layout (offsets in floats) ----
#define WS_DEG      0            // N ints
#define WS_ROWPTR   100096       // N+1 ints
#define WS_CURSOR   200192       // N ints
#define WS_INV      300288       // N floats
#define WS_AGGE     400384       // N*8 floats
#define WS_SUMS     1200384      // 10*256 (per-t: sum[128], sumsq[128])
#define WS_ZEND     1202944      // end of single upfront zero region
#define WS_CSRSRC   1202944      // E ints
#define WS_AGGX     2802944      // N*64
#define WS_HSEQ     9202944      // T*B*H = 2621440
#define WS_H        11824384     // B*H
#define WS_C        12086528     // B*H (adjacent to WS_H for one memset)
#define WS_WIT      12348672     // 128*512
#define WS_WHT      12414208     // 128*512

// ---------------- degree ----------------
__global__ void k_deg(const int* __restrict__ ei, int* __restrict__ deg) {
    int e = blockIdx.x * blockDim.x + threadIdx.x;
    if (e < E_EDGES) atomicAdd(&deg[ei[E_EDGES + e]], 1);
}

// ---------------- exclusive scan of deg -> rowptr, cursor, inv (single block) ----------------
#define SCAN_T 1024
#define SCAN_CH 98   // 1024*98 = 100352 >= 100000
__global__ __launch_bounds__(SCAN_T) void k_scan(const int* __restrict__ deg,
        int* __restrict__ rowptr, int* __restrict__ cursor, float* __restrict__ inv) {
    __shared__ int part[SCAN_T];
    int li = threadIdx.x;
    int lo = li * SCAN_CH;
    int hi = lo + SCAN_CH; if (hi > N_NODES) hi = N_NODES;
    int s = 0;
    for (int j = lo; j < hi; j++) s += deg[j];
    part[li] = s;
    __syncthreads();
    // Hillis-Steele inclusive scan
    for (int off = 1; off < SCAN_T; off <<= 1) {
        int v = (li >= off) ? part[li - off] : 0;
        __syncthreads();
        part[li] += v;
        __syncthreads();
    }
    int base = part[li] - s;   // exclusive prefix for this chunk
    for (int j = lo; j < hi; j++) {
        int d = deg[j];
        rowptr[j] = base;
        cursor[j] = base;
        inv[j] = 1.0f / (float)(d > 1 ? d : 1);
        base += d;
    }
    if (li == SCAN_T - 1) rowptr[N_NODES] = part[SCAN_T - 1];
}

// ---------------- CSR fill: csr_src sorted by dst ----------------
__global__ void k_fill(const int* __restrict__ ei, int* __restrict__ cursor,
                       int* __restrict__ csr_src) {
    int e = blockIdx.x * blockDim.x + threadIdx.x;
    if (e < E_EDGES) {
        int dst = ei[E_EDGES + e];
        int pos = atomicAdd(&cursor[dst], 1);
        csr_src[pos] = ei[e];
    }
}

// ---------------- edge-attr aggregation (t-invariant, once) ----------------
__global__ void k_agge(const int* __restrict__ ei, const float* __restrict__ ea,
                       float* __restrict__ agge) {
    int i = blockIdx.x * blockDim.x + threadIdx.x;   // over E*8
    if (i < E_EDGES * ED_DIM) {
        int e = i >> 3, j = i & 7;
        int dst = ei[E_EDGES + e];
        atomicAdd(&agge[dst * ED_DIM + j], ea[i]);
    }
}

__global__ void k_scale_agge(float* __restrict__ agge, const float* __restrict__ inv) {
    int i = blockIdx.x * blockDim.x + threadIdx.x;
    if (i < N_NODES * ED_DIM) agge[i] *= inv[i >> 3];
}

// ---------------- LSTM weight pre-transpose (once) ----------------
__global__ void k_transpose(const float* __restrict__ wih, const float* __restrict__ whh,
                            float* __restrict__ wiT, float* __restrict__ whT) {
    int i = blockIdx.x * blockDim.x + threadIdx.x;   // over 512*128, output-centric
    if (i < G4H * H_DIM) {
        int k = i >> 9, j = i & 511;
        wiT[i] = wih[j * H_DIM + k];
        whT[i] = whh[j * H_DIM + k];
    }
}

// ---------------- per-t CSR gather: aggx[n] = inv[n] * sum_{e in in(n)} x_t[src] ----------------
// one wave per node, lane = feature; unroll x4 for outstanding loads
__global__ __launch_bounds__(256) void k_gather(const float* __restrict__ x,
        const int* __restrict__ rowptr, const int* __restrict__ csr_src,
        const float* __restrict__ inv, float* __restrict__ aggx, int t) {
    int node = blockIdx.x * 4 + (threadIdx.x >> 6);
    int lane = threadIdx.x & 63;
    int beg = rowptr[node], end = rowptr[node + 1];
    const float* xt = x + t * F_DIM + lane;
    float acc = 0.f;
    int e = beg;
    for (; e + 3 < end; e += 4) {
        int s0 = csr_src[e], s1 = csr_src[e + 1], s2 = csr_src[e + 2], s3 = csr_src[e + 3];
        float v0 = xt[s0 * TF], v1 = xt[s1 * TF], v2 = xt[s2 * TF], v3 = xt[s3 * TF];
        acc += (v0 + v1) + (v2 + v3);
    }
    for (; e < end; e++) acc += xt[csr_src[e] * TF];
    aggx[node * F_DIM + lane] = acc * inv[node];
}

// ---------------- BN stats: sum & sumsq of (xin @ W) over all N rows ----------------
// block = 256 threads, 32 rows; thread computes 4x4 register tile; K in 2 chunks of 68
#define XPAD 140
__global__ __launch_bounds__(256) void k_stats(const float* __restrict__ x,
        const float* __restrict__ aggx, const float* __restrict__ agge,
        const float* __restrict__ wself, const float* __restrict__ wmsg,
        float* __restrict__ sums, int t) {
    __shared__ float s_xin[32 * XPAD];
    __shared__ float s_w[68 * 128];
    __shared__ float s_sum[H_DIM], s_sq[H_DIM];
    int tid  = threadIdx.x;
    int row0 = blockIdx.x * 32;

    // fill s_xin with float4 loads: per row 16 x-quads + 16 aggx-quads + 2 agge-quads
    {
        const float4* x4    = (const float4*)(x + t * F_DIM);
        const float4* aggx4 = (const float4*)aggx;
        const float4* agge4 = (const float4*)agge;
        for (int i = tid; i < 32 * 34; i += 256) {
            int r = i / 34, q = i - r * 34;
            int n = row0 + r;
            float4 v;
            if (q < 16)      v = x4[n * (TF / 4) + q];
            else if (q < 32) v = aggx4[n * 16 + (q - 16)];
            else             v = agge4[n * 2 + (q - 32)];
            *(float4*)&s_xin[r * XPAD + q * 4] = v;
        }
    }
    if (tid < H_DIM) { s_sum[tid] = 0.f; s_sq[tid] = 0.f; }

    int tx = tid & 31, ty = tid >> 5;           // cols tx*4+j, rows ty*4+i
    float acc[4][4];
    #pragma unroll
    for (int i = 0; i < 4; i++)
        #pragma unroll
        for (int j = 0; j < 4; j++) acc[i][j] = 0.f;

    for (int kc = 0; kc < 2; kc++) {
        __syncthreads();   // (kc=0) s_xin ready; (kc=1) prior s_w reads done
        for (int i = tid; i < 68 * 128; i += 256) {
            int gk = kc * 68 + (i >> 7), c = i & 127;
            s_w[i] = (gk < 64) ? wself[gk * 128 + c] : wmsg[(gk - 64) * 128 + c];
        }
        __syncthreads();
        const float4* s_w4 = (const float4*)s_w;
        for (int k2 = 0; k2 < 68; k2++) {
            float a[4];
            #pragma unroll
            for (int i = 0; i < 4; i++) a[i] = s_xin[(ty * 4 + i) * XPAD + kc * 68 + k2];
            float4 b4 = s_w4[k2 * 32 + tx];
            #pragma unroll
            for (int i = 0; i < 4; i++) {
                acc[i][0] += a[i] * b4.x;
                acc[i][1] += a[i] * b4.y;
                acc[i][2] += a[i] * b4.z;
                acc[i][3] += a[i] * b4.w;
            }
        }
    }

    #pragma unroll
    for (int j = 0; j < 4; j++) {
        int h = tx * 4 + j;
        float cs = 0.f, cq = 0.f;
        #pragma unroll
        for (int i = 0; i < 4; i++) { cs += acc[i][j]; cq += acc[i][j] * acc[i][j]; }
        atomicAdd(&s_sum[h], cs);
        atomicAdd(&s_sq[h], cq);
    }
    __syncthreads();
    if (tid < H_DIM) {
        atomicAdd(&sums[tid], s_sum[tid]);
        atomicAdd(&sums[H_DIM + tid], s_sq[tid]);
    }
}

// ---------------- focal rows: h_seq[t,b,:] = relu(BN(xin[ptr[b]] @ W)), BN folded inline ----------------
__global__ __launch_bounds__(128) void k_focal(const float* __restrict__ x,
        const float* __restrict__ aggx, const float* __restrict__ agge,
        const float* __restrict__ wself, const float* __restrict__ wmsg,
        const float* __restrict__ sums, const float* __restrict__ gamma,
        const float* __restrict__ beta, const int* __restrict__ ptr,
        float* __restrict__ hseq, int t) {
    __shared__ float s_xin[K_IN];
    int b   = blockIdx.x;
    int n   = ptr[b];
    int tid = threadIdx.x;
    if (tid < K_IN - 64) {
        int k = 64 + tid;
        s_xin[k] = (k < 128) ? aggx[n * F_DIM + (k - 64)] : agge[n * ED_DIM + (k - 128)];
    }
    {
        int k = tid & 63;   // 2 copies write same value; benign
        s_xin[k] = x[n * TF + t * F_DIM + k];
    }
    __syncthreads();
    int h = tid;
    float acc = 0.f;
    #pragma unroll 8
    for (int k = 0; k < F_DIM; k++) acc += s_xin[k] * wself[k * H_DIM + h];
    #pragma unroll 8
    for (int k = 0; k < 72; k++)    acc += s_xin[F_DIM + k] * wmsg[k * H_DIM + h];
    // inline BN finalize (biases are zero / cancel in mean subtraction)
    float mean = sums[h] * (1.0f / N_NODES);
    float var  = sums[H_DIM + h] * (1.0f / N_NODES) - mean * mean;
    var = fmaxf(var, 0.f);
    float istd = 1.0f / sqrtf(var + 1e-5f);
    float sc = gamma[h] * istd;
    float sh = beta[h] - mean * sc;
    float v = acc * sc + sh;
    hseq[(t * B_BATCH + b) * H_DIM + h] = fmaxf(v, 0.f);
}

// ---------------- one fused LSTM step: gates GEMM + pointwise update ----------------
__global__ __launch_bounds__(512) void k_lstm(const float* __restrict__ hseq_t,
        const float* __restrict__ wiT, const float* __restrict__ whT,
        const float* __restrict__ bih, const float* __restrict__ bhh,
        float* __restrict__ h, float* __restrict__ c) {
    __shared__ float s_hin[16][H_DIM];
    __shared__ float s_hpr[16][H_DIM];
    __shared__ float s_g[16][G4H];
    int tid  = threadIdx.x;
    int row0 = blockIdx.x * 16;
    for (int idx = tid; idx < 16 * H_DIM; idx += 512) {
        int r = idx >> 7, k = idx & 127;
        s_hin[r][k] = hseq_t[(row0 + r) * H_DIM + k];
        s_hpr[r][k] = h[(row0 + r) * H_DIM + k];
    }
    __syncthreads();
    int j = tid;
    float acc[16];
    #pragma unroll
    for (int r = 0; r < 16; r++) acc[r] = 0.f;
    for (int k = 0; k < H_DIM; k++) {
        float wi = wiT[k * G4H + j];
        float wh = whT[k * G4H + j];
        #pragma unroll
        for (int r = 0; r < 16; r++) acc[r] += s_hin[r][k] * wi + s_hpr[r][k] * wh;
    }
    float bias = bih[j] + bhh[j];
    #pragma unroll
    for (int r = 0; r < 16; r++) s_g[r][j] = acc[r] + bias;
    __syncthreads();
    for (int m = tid; m < 16 * H_DIM; m += 512) {
        int r = m >> 7, hh = m & 127;
        float gi = s_g[r][hh];
        float gf = s_g[r][hh + 128];
        float gg = s_g[r][hh + 256];
        float go = s_g[r][hh + 384];
        float si = 1.f / (1.f + expf(-gi));
        float sf = 1.f / (1.f + expf(-gf));
        float so = 1.f / (1.f + expf(-go));
        float tg = tanhf(gg);
        int gidx = (row0 + r) * H_DIM + hh;
        float cn = sf * c[gidx] + si * tg;
        c[gidx] = cn;
        h[gidx] = so * tanhf(cn);
    }
}

// ---------------- classifier ----------------
__global__ void k_cls(const float* __restrict__ h, const float* __restrict__ wcls,
                      const float* __restrict__ bcls, float* __restrict__ out) {
    int i = blockIdx.x * blockDim.x + threadIdx.x;
    if (i < B_BATCH * C_CLS) {
        int b = i >> 1, cc = i & 1;
        float acc = bcls[cc];
        for (int k = 0; k < H_DIM; k++) acc += h[b * H_DIM + k] * wcls[k * C_CLS + cc];
        out[i] = acc;
    }
}

extern "C" void kernel_launch(void* const* d_in, const int* in_sizes, int n_in,
                              void* d_out, int out_size, void* d_ws, size_t ws_size,
                              hipStream_t stream) {
    const float* x     = (const float*)d_in[0];
    const int*   ei    = (const int*)d_in[1];
    const float* ea    = (const float*)d_in[2];
    const int*   ptr   = (const int*)d_in[3];
    const float* wmsg  = (const float*)d_in[4];
    const float* wself = (const float*)d_in[6];
    const float* gamma = (const float*)d_in[8];
    const float* beta  = (const float*)d_in[9];
    const float* wih   = (const float*)d_in[10];
    const float* whh   = (const float*)d_in[11];
    const float* bih   = (const float*)d_in[12];
    const float* bhh   = (const float*)d_in[13];
    const float* wcls  = (const float*)d_in[14];
    const float* bcls  = (const float*)d_in[15];
    float* out = (float*)d_out;

    float* ws     = (float*)d_ws;
    int*   deg    = (int*)(ws + WS_DEG);
    int*   rowptr = (int*)(ws + WS_ROWPTR);
    int*   cursor = (int*)(ws + WS_CURSOR);
    float* inv    = ws + WS_INV;
    float* agge   = ws + WS_AGGE;
    float* sums   = ws + WS_SUMS;
    int*   csrs   = (int*)(ws + WS_CSRSRC);
    float* aggx   = ws + WS_AGGX;
    float* hseq   = ws + WS_HSEQ;
    float* hbuf   = ws + WS_H;
    float* cbuf   = ws + WS_C;
    float* wiT    = ws + WS_WIT;
    float* whT    = ws + WS_WHT;

    // one upfront zero of [deg..sums]; one for [h,c]
    hipMemsetAsync(ws, 0, (size_t)WS_ZEND * 4, stream);
    hipMemsetAsync(ws + WS_H, 0, (size_t)(2 * B_BATCH * H_DIM) * 4, stream);

    k_deg<<<(E_EDGES + 255) / 256, 256, 0, stream>>>(ei, deg);
    k_scan<<<1, SCAN_T, 0, stream>>>(deg, rowptr, cursor, inv);
    k_agge<<<(E_EDGES * ED_DIM + 255) / 256, 256, 0, stream>>>(ei, ea, agge);
    k_scale_agge<<<(N_NODES * ED_DIM + 255) / 256, 256, 0, stream>>>(agge, inv);
    k_fill<<<(E_EDGES + 255) / 256, 256, 0, stream>>>(ei, cursor, csrs);
    k_transpose<<<(G4H * H_DIM + 255) / 256, 256, 0, stream>>>(wih, whh, wiT, whT);

    for (int t = 0; t < T_STEPS; t++) {
        float* sums_t = sums + t * 256;
        k_gather<<<N_NODES / 4, 256, 0, stream>>>(x, rowptr, csrs, inv, aggx, t);
        k_stats<<<N_NODES / 32, 256, 0, stream>>>(x, aggx, agge, wself, wmsg, sums_t, t);
        k_focal<<<B_BATCH, 128, 0, stream>>>(x, aggx, agge, wself, wmsg, sums_t,
                                             gamma, beta, ptr, hseq, t);
    }
    for (int t = 0; t < T_STEPS; t++) {
        k_lstm<<<B_BATCH / 16, 512, 0, stream>>>(hseq + (size_t)t * B_BATCH * H_DIM,
                                                 wiT, whT, bih, bhh, hbuf, cbuf);
    }
    k_cls<<<(B_BATCH * C_CLS + 255) / 256, 256, 0, stream>>>(hbuf, wcls, bcls, out);
}

// Round 4
// 2761.728 us; speedup vs baseline: 2.1906x; 1.1717x over previous
//
#include <hip/hip_runtime.h>
#include <hip/hip_bf16.h>

#define N_NODES 100000
#define T_STEPS 10
#define F_DIM   64
#define E_EDGES 1600000
#define ED_DIM  8
#define H_DIM   128
#define B_BATCH 2048
#define C_CLS   2
#define TF      640      // T*F
#define K_IN    136      // F (self) + F (agg-x) + ED (agg-edge)
#define G4H     512      // 4*H
#define KPAD    160      // K padded to 5 MFMA k-tiles of 32
#define XROW    168      // LDS row pitch in bf16 elements (pad breaks bank stride)
#define PBLK    98       // scan blocks: 98*1024 >= 100000

typedef __attribute__((ext_vector_type(8))) short short8;
typedef __attribute__((ext_vector_type(4))) float f32x4;

__device__ __forceinline__ short f2bs(float f) {
    __hip_bfloat16 h = __float2bfloat16(f);
    return *(short*)&h;
}

// ---- workspace layout (offsets in floats) ----
#define WS_DEG      0            // N ints
#define WS_ROWPTR   100096       // N+1 ints
#define WS_CURSOR   200192       // N ints
#define WS_INV      300288       // N floats
#define WS_AGGE     400384       // N*8 floats
#define WS_SUMS     1200384      // 10*256 (per-t: sum[128], sumsq[128])
#define WS_ZEND     1202944      // end of single upfront zero region
#define WS_CSRSRC   1202944      // E ints
#define WS_AGGX     2802944      // N*64
#define WS_HSEQ     9202944      // T*B*H = 2621440
#define WS_H        11824384     // B*H
#define WS_C        12086528     // B*H (adjacent to WS_H for one memset)
#define WS_WIT      12348672     // 128*512
#define WS_WHT      12414208     // 128*512
#define WS_WB       12479744     // 20480 bf16 = 10240 floats (MFMA B-layout weights)
#define WS_PART     12489984     // 98 ints
#define WS_BOFF     12490112     // 98 ints

// ---------------- degree ----------------
__global__ void k_deg(const int* __restrict__ ei, int* __restrict__ deg) {
    int e = blockIdx.x * blockDim.x + threadIdx.x;
    if (e < E_EDGES) atomicAdd(&deg[ei[E_EDGES + e]], 1);
}

// ---------------- parallel scan: block partials ----------------
__global__ __launch_bounds__(1024) void k_part(const int* __restrict__ deg,
                                               int* __restrict__ part) {
    __shared__ int red[1024];
    int gid = blockIdx.x * 1024 + threadIdx.x;
    red[threadIdx.x] = (gid < N_NODES) ? deg[gid] : 0;
    __syncthreads();
    for (int off = 512; off > 0; off >>= 1) {
        if (threadIdx.x < off) red[threadIdx.x] += red[threadIdx.x + off];
        __syncthreads();
    }
    if (threadIdx.x == 0) part[blockIdx.x] = red[0];
}

// ---------------- scan the 98 partials -> exclusive block offsets ----------------
__global__ __launch_bounds__(128) void k_scanpart(const int* __restrict__ part,
        int* __restrict__ boff, int* __restrict__ rowptr) {
    __shared__ int buf[128];
    int li = threadIdx.x;
    int v = (li < PBLK) ? part[li] : 0;
    buf[li] = v;
    __syncthreads();
    for (int off = 1; off < 128; off <<= 1) {
        int u = (li >= off) ? buf[li - off] : 0;
        __syncthreads();
        buf[li] += u;
        __syncthreads();
    }
    if (li < PBLK) boff[li] = buf[li] - v;
    if (li == 0) rowptr[N_NODES] = E_EDGES;   // sum of all degrees == E
}

// ---------------- fill rowptr/cursor/inv with block-local scan + offset ----------------
__global__ __launch_bounds__(1024) void k_rowfill(const int* __restrict__ deg,
        const int* __restrict__ boff, int* __restrict__ rowptr,
        int* __restrict__ cursor, float* __restrict__ inv) {
    __shared__ int buf[1024];
    int li = threadIdx.x;
    int gid = blockIdx.x * 1024 + li;
    int d = (gid < N_NODES) ? deg[gid] : 0;
    buf[li] = d;
    __syncthreads();
    for (int off = 1; off < 1024; off <<= 1) {
        int u = (li >= off) ? buf[li - off] : 0;
        __syncthreads();
        buf[li] += u;
        __syncthreads();
    }
    if (gid < N_NODES) {
        int excl = boff[blockIdx.x] + buf[li] - d;
        rowptr[gid] = excl;
        cursor[gid] = excl;
        inv[gid] = 1.0f / (float)(d > 1 ? d : 1);
    }
}

// ---------------- CSR fill: csr_src sorted by dst ----------------
__global__ void k_fill(const int* __restrict__ ei, int* __restrict__ cursor,
                       int* __restrict__ csr_src) {
    int e = blockIdx.x * blockDim.x + threadIdx.x;
    if (e < E_EDGES) {
        int dst = ei[E_EDGES + e];
        int pos = atomicAdd(&cursor[dst], 1);
        csr_src[pos] = ei[e];
    }
}

// ---------------- edge-attr aggregation (t-invariant, once) ----------------
__global__ void k_agge(const int* __restrict__ ei, const float* __restrict__ ea,
                       float* __restrict__ agge) {
    int i = blockIdx.x * blockDim.x + threadIdx.x;   // over E*8
    if (i < E_EDGES * ED_DIM) {
        int e = i >> 3, j = i & 7;
        int dst = ei[E_EDGES + e];
        atomicAdd(&agge[dst * ED_DIM + j], ea[i]);
    }
}

__global__ void k_scale_agge(float* __restrict__ agge, const float* __restrict__ inv) {
    int i = blockIdx.x * blockDim.x + threadIdx.x;
    if (i < N_NODES * ED_DIM) agge[i] *= inv[i >> 3];
}

// ---------------- LSTM weight pre-transpose (once) ----------------
__global__ void k_transpose(const float* __restrict__ wih, const float* __restrict__ whh,
                            float* __restrict__ wiT, float* __restrict__ whT) {
    int i = blockIdx.x * blockDim.x + threadIdx.x;   // over 512*128, output-centric
    if (i < G4H * H_DIM) {
        int k = i >> 9, j = i & 511;
        wiT[i] = wih[j * H_DIM + k];
        whT[i] = whh[j * H_DIM + k];
    }
}

// ---------------- pack [wself; wmsg] (K=136 pad 160) into MFMA B-frag layout, bf16 ----------------
// wB[kt*4096 + n*32 + q*8 + j] = bf16(W[kt*32 + q*8 + j][n])
__global__ void k_wprep(const float* __restrict__ wself, const float* __restrict__ wmsg,
                        short* __restrict__ wB) {
    int i = blockIdx.x * blockDim.x + threadIdx.x;   // over 5*4096 = 20480
    if (i < 20480) {
        int j = i & 7, q = (i >> 3) & 3, n = (i >> 5) & 127, kt = i >> 12;
        int k = kt * 32 + q * 8 + j;
        float v = 0.f;
        if (k < 64)       v = wself[k * 128 + n];
        else if (k < 136) v = wmsg[(k - 64) * 128 + n];
        wB[i] = f2bs(v);
    }
}

// ---------------- per-t CSR gather: aggx[n] = inv[n] * sum_{e in in(n)} x_t[src] ----------------
__global__ __launch_bounds__(256) void k_gather(const float* __restrict__ x,
        const int* __restrict__ rowptr, const int* __restrict__ csr_src,
        const float* __restrict__ inv, float* __restrict__ aggx, int t) {
    int node = blockIdx.x * 4 + (threadIdx.x >> 6);
    int lane = threadIdx.x & 63;
    int beg = rowptr[node], end = rowptr[node + 1];
    const float* xt = x + t * F_DIM + lane;
    float acc = 0.f;
    int e = beg;
    for (; e + 3 < end; e += 4) {
        int s0 = csr_src[e], s1 = csr_src[e + 1], s2 = csr_src[e + 2], s3 = csr_src[e + 3];
        float v0 = xt[s0 * TF], v1 = xt[s1 * TF], v2 = xt[s2 * TF], v3 = xt[s3 * TF];
        acc += (v0 + v1) + (v2 + v3);
    }
    for (; e < end; e++) acc += xt[csr_src[e] * TF];
    aggx[node * F_DIM + lane] = acc * inv[node];
}

// ---------------- BN stats via bf16 MFMA: sum & sumsq of (xin @ W) ----------------
// block = 256 thr (4 waves), 32 rows x 128 cols; wave w: cols w*32..w*32+31
__global__ __launch_bounds__(256) void k_stats(const float* __restrict__ x,
        const float* __restrict__ aggx, const float* __restrict__ agge,
        const short* __restrict__ wB, float* __restrict__ sums, int t) {
    __shared__ __align__(16) short s_xa[32 * XROW];
    int tid  = threadIdx.x;
    int row0 = blockIdx.x * 32;
    const float4* x4    = (const float4*)x;
    const float4* aggx4 = (const float4*)aggx;
    const float4* agge4 = (const float4*)agge;
    // stage 32 rows x 160 (pad-zeroed) bf16 into LDS
    for (int i = tid; i < 32 * 40; i += 256) {
        int r = i / 40, q = i - r * 40;
        int n = row0 + r;
        float4 v = make_float4(0.f, 0.f, 0.f, 0.f);
        if (q < 16)      v = x4[n * 160 + t * 16 + q];
        else if (q < 32) v = aggx4[n * 16 + (q - 16)];
        else if (q < 34) v = agge4[n * 2 + (q - 32)];
        short4 s;
        s.x = f2bs(v.x); s.y = f2bs(v.y); s.z = f2bs(v.z); s.w = f2bs(v.w);
        *(short4*)&s_xa[r * XROW + q * 4] = s;
    }
    __syncthreads();

    int wave = tid >> 6, lane = tid & 63;
    int q = lane >> 4, m = lane & 15;
    int n0 = wave * 32;
    f32x4 a00 = {0.f,0.f,0.f,0.f}, a01 = a00, a10 = a00, a11 = a00;
    #pragma unroll
    for (int kt = 0; kt < 5; kt++) {
        short8 af0 = *(const short8*)&s_xa[m * XROW + kt * 32 + q * 8];
        short8 af1 = *(const short8*)&s_xa[(16 + m) * XROW + kt * 32 + q * 8];
        short8 bf0 = *(const short8*)&wB[kt * 4096 + (n0 + m) * 32 + q * 8];
        short8 bf1 = *(const short8*)&wB[kt * 4096 + (n0 + 16 + m) * 32 + q * 8];
        a00 = __builtin_amdgcn_mfma_f32_16x16x32_bf16(af0, bf0, a00, 0, 0, 0);
        a10 = __builtin_amdgcn_mfma_f32_16x16x32_bf16(af1, bf0, a10, 0, 0, 0);
        a01 = __builtin_amdgcn_mfma_f32_16x16x32_bf16(af0, bf1, a01, 0, 0, 0);
        a11 = __builtin_amdgcn_mfma_f32_16x16x32_bf16(af1, bf1, a11, 0, 0, 0);
    }
    // epilogue: per-col sum & sumsq; C layout: col = lane&15, row = q*4+reg
    #pragma unroll
    for (int ct = 0; ct < 2; ct++) {
        float cs = 0.f, cq = 0.f;
        #pragma unroll
        for (int g = 0; g < 4; g++) {
            float v0 = (ct == 0) ? a00[g] : a01[g];
            float v1 = (ct == 0) ? a10[g] : a11[g];
            cs += v0 + v1;
            cq += v0 * v0 + v1 * v1;
        }
        cs += __shfl_xor(cs, 16, 64); cq += __shfl_xor(cq, 16, 64);
        cs += __shfl_xor(cs, 32, 64); cq += __shfl_xor(cq, 32, 64);
        if (lane < 16) {
            int col = n0 + ct * 16 + m;
            atomicAdd(&sums[col], cs);
            atomicAdd(&sums[128 + col], cq);
        }
    }
}

// ---------------- focal rows: h_seq[t,b,:] = relu(BN(xin[ptr[b]] @ W)), fp32 exact ----------------
__global__ __launch_bounds__(128) void k_focal(const float* __restrict__ x,
        const float* __restrict__ aggx, const float* __restrict__ agge,
        const float* __restrict__ wself, const float* __restrict__ wmsg,
        const float* __restrict__ sums, const float* __restrict__ gamma,
        const float* __restrict__ beta, const int* __restrict__ ptr,
        float* __restrict__ hseq, int t) {
    __shared__ float s_xin[K_IN];
    int b   = blockIdx.x;
    int n   = ptr[b];
    int tid = threadIdx.x;
    if (tid < K_IN - 64) {
        int k = 64 + tid;
        s_xin[k] = (k < 128) ? aggx[n * F_DIM + (k - 64)] : agge[n * ED_DIM + (k - 128)];
    }
    {
        int k = tid & 63;   // 2 copies write same value; benign
        s_xin[k] = x[n * TF + t * F_DIM + k];
    }
    __syncthreads();
    int h = tid;
    float acc = 0.f;
    #pragma unroll 8
    for (int k = 0; k < F_DIM; k++) acc += s_xin[k] * wself[k * H_DIM + h];
    #pragma unroll 8
    for (int k = 0; k < 72; k++)    acc += s_xin[F_DIM + k] * wmsg[k * H_DIM + h];
    float mean = sums[h] * (1.0f / N_NODES);
    float var  = sums[H_DIM + h] * (1.0f / N_NODES) - mean * mean;
    var = fmaxf(var, 0.f);
    float istd = 1.0f / sqrtf(var + 1e-5f);
    float sc = gamma[h] * istd;
    float sh = beta[h] - mean * sc;
    float v = acc * sc + sh;
    hseq[(t * B_BATCH + b) * H_DIM + h] = fmaxf(v, 0.f);
}

// ---------------- one fused LSTM step: gates GEMM + pointwise update ----------------
__global__ __launch_bounds__(512) void k_lstm(const float* __restrict__ hseq_t,
        const float* __restrict__ wiT, const float* __restrict__ whT,
        const float* __restrict__ bih, const float* __restrict__ bhh,
        float* __restrict__ h, float* __restrict__ c) {
    __shared__ float s_hin[16][H_DIM];
    __shared__ float s_hpr[16][H_DIM];
    __shared__ float s_g[16][G4H];
    int tid  = threadIdx.x;
    int row0 = blockIdx.x * 16;
    for (int idx = tid; idx < 16 * H_DIM; idx += 512) {
        int r = idx >> 7, k = idx & 127;
        s_hin[r][k] = hseq_t[(row0 + r) * H_DIM + k];
        s_hpr[r][k] = h[(row0 + r) * H_DIM + k];
    }
    __syncthreads();
    int j = tid;
    float acc[16];
    #pragma unroll
    for (int r = 0; r < 16; r++) acc[r] = 0.f;
    for (int k = 0; k < H_DIM; k++) {
        float wi = wiT[k * G4H + j];
        float wh = whT[k * G4H + j];
        #pragma unroll
        for (int r = 0; r < 16; r++) acc[r] += s_hin[r][k] * wi + s_hpr[r][k] * wh;
    }
    float bias = bih[j] + bhh[j];
    #pragma unroll
    for (int r = 0; r < 16; r++) s_g[r][j] = acc[r] + bias;
    __syncthreads();
    for (int m = tid; m < 16 * H_DIM; m += 512) {
        int r = m >> 7, hh = m & 127;
        float gi = s_g[r][hh];
        float gf = s_g[r][hh + 128];
        float gg = s_g[r][hh + 256];
        float go = s_g[r][hh + 384];
        float si = 1.f / (1.f + expf(-gi));
        float sf = 1.f / (1.f + expf(-gf));
        float so = 1.f / (1.f + expf(-go));
        float tg = tanhf(gg);
        int gidx = (row0 + r) * H_DIM + hh;
        float cn = sf * c[gidx] + si * tg;
        c[gidx] = cn;
        h[gidx] = so * tanhf(cn);
    }
}

// ---------------- classifier ----------------
__global__ void k_cls(const float* __restrict__ h, const float* __restrict__ wcls,
                      const float* __restrict__ bcls, float* __restrict__ out) {
    int i = blockIdx.x * blockDim.x + threadIdx.x;
    if (i < B_BATCH * C_CLS) {
        int b = i >> 1, cc = i & 1;
        float acc = bcls[cc];
        for (int k = 0; k < H_DIM; k++) acc += h[b * H_DIM + k] * wcls[k * C_CLS + cc];
        out[i] = acc;
    }
}

extern "C" void kernel_launch(void* const* d_in, const int* in_sizes, int n_in,
                              void* d_out, int out_size, void* d_ws, size_t ws_size,
                              hipStream_t stream) {
    const float* x     = (const float*)d_in[0];
    const int*   ei    = (const int*)d_in[1];
    const float* ea    = (const float*)d_in[2];
    const int*   ptr   = (const int*)d_in[3];
    const float* wmsg  = (const float*)d_in[4];
    const float* wself = (const float*)d_in[6];
    const float* gamma = (const float*)d_in[8];
    const float* beta  = (const float*)d_in[9];
    const float* wih   = (const float*)d_in[10];
    const float* whh   = (const float*)d_in[11];
    const float* bih   = (const float*)d_in[12];
    const float* bhh   = (const float*)d_in[13];
    const float* wcls  = (const float*)d_in[14];
    const float* bcls  = (const float*)d_in[15];
    float* out = (float*)d_out;

    float* ws     = (float*)d_ws;
    int*   deg    = (int*)(ws + WS_DEG);
    int*   rowptr = (int*)(ws + WS_ROWPTR);
    int*   cursor = (int*)(ws + WS_CURSOR);
    float* inv    = ws + WS_INV;
    float* agge   = ws + WS_AGGE;
    float* sums   = ws + WS_SUMS;
    int*   csrs   = (int*)(ws + WS_CSRSRC);
    float* aggx   = ws + WS_AGGX;
    float* hseq   = ws + WS_HSEQ;
    float* hbuf   = ws + WS_H;
    float* cbuf   = ws + WS_C;
    float* wiT    = ws + WS_WIT;
    float* whT    = ws + WS_WHT;
    short* wB     = (short*)(ws + WS_WB);
    int*   part   = (int*)(ws + WS_PART);
    int*   boff   = (int*)(ws + WS_BOFF);

    // one upfront zero of [deg..sums]; one for [h,c]
    hipMemsetAsync(ws, 0, (size_t)WS_ZEND * 4, stream);
    hipMemsetAsync(ws + WS_H, 0, (size_t)(2 * B_BATCH * H_DIM) * 4, stream);

    k_deg<<<(E_EDGES + 255) / 256, 256, 0, stream>>>(ei, deg);
    k_part<<<PBLK, 1024, 0, stream>>>(deg, part);
    k_scanpart<<<1, 128, 0, stream>>>(part, boff, rowptr);
    k_rowfill<<<PBLK, 1024, 0, stream>>>(deg, boff, rowptr, cursor, inv);
    k_agge<<<(E_EDGES * ED_DIM + 255) / 256, 256, 0, stream>>>(ei, ea, agge);
    k_scale_agge<<<(N_NODES * ED_DIM + 255) / 256, 256, 0, stream>>>(agge, inv);
    k_fill<<<(E_EDGES + 255) / 256, 256, 0, stream>>>(ei, cursor, csrs);
    k_transpose<<<(G4H * H_DIM + 255) / 256, 256, 0, stream>>>(wih, whh, wiT, whT);
    k_wprep<<<80, 256, 0, stream>>>(wself, wmsg, wB);

    for (int t = 0; t < T_STEPS; t++) {
        float* sums_t = sums + t * 256;
        k_gather<<<N_NODES / 4, 256, 0, stream>>>(x, rowptr, csrs, inv, aggx, t);
        k_stats<<<N_NODES / 32, 256, 0, stream>>>(x, aggx, agge, wB, sums_t, t);
        k_focal<<<B_BATCH, 128, 0, stream>>>(x, aggx, agge, wself, wmsg, sums_t,
                                             gamma, beta, ptr, hseq, t);
    }
    for (int t = 0; t < T_STEPS; t++) {
        k_lstm<<<B_BATCH / 16, 512, 0, stream>>>(hseq + (size_t)t * B_BATCH * H_DIM,
                                                 wiT, whT, bih, bhh, hbuf, cbuf);
    }
    k_cls<<<(B_BATCH * C_CLS + 255) / 256, 256, 0, stream>>>(hbuf, wcls, bcls, out);
}

// Round 5
// 2351.271 us; speedup vs baseline: 2.5731x; 1.1746x over previous
//
#include <hip/hip_runtime.h>
#include <hip/hip_bf16.h>

#define N_NODES 100000
#define T_STEPS 10
#define F_DIM   64
#define E_EDGES 1600000
#define ED_DIM  8
#define H_DIM   128
#define B_BATCH 2048
#define C_CLS   2
#define TF      640      // T*F
#define K_IN    136      // F (self) + F (agg-x) + ED (agg-edge)
#define G4H     512      // 4*H
#define XROW    168      // stats LDS row pitch in bf16 elements
#define PBLK    98       // scan blocks: 98*1024 >= 100000

typedef __attribute__((ext_vector_type(8))) short short8;
typedef __attribute__((ext_vector_type(4))) float f32x4;

__device__ __forceinline__ unsigned short fbs(float f) {
    __hip_bfloat16 h = __float2bfloat16(f);
    return *(unsigned short*)&h;
}
__device__ __forceinline__ float bs2f(unsigned short u) {
    unsigned int v = ((unsigned int)u) << 16;
    return __uint_as_float(v);
}
__device__ __forceinline__ unsigned int pack2(float lo, float hi) {
    return (unsigned int)fbs(lo) | ((unsigned int)fbs(hi) << 16);
}

// ---- workspace layout (offsets in floats) ----
#define WS_DEG      0            // N ints
#define WS_ROWPTR   100096       // N+1 ints
#define WS_CURSOR   200192       // N ints
#define WS_INV      300288       // N floats
#define WS_AGGE     400384       // N*8 fp32 (scaled in place; focal reads)
#define WS_SUMS     1200384      // 10*256
#define WS_ZEND     1202944      // end of single upfront zero region
#define WS_CSRSRC   1202944      // E ints
#define WS_AGGXB    2802944      // N*64 bf16 (3.2M float slots)
#define WS_AGGEB    6002944      // N*8 bf16
#define WS_HSEQB    6402944      // T*B*H bf16
#define WS_HN       7713664      // B*H fp32
#define WS_WB       7975808      // 20480 bf16 (stats W, MFMA B-layout)
#define WS_WL       7986048      // 131072 bf16 (LSTM W, permuted MFMA B-layout)
#define WS_PART     8051584      // 98 ints
#define WS_BOFF     8051712      // 98 ints
#define WS_XB       8051840      // N*TF bf16 (32M float slots)

// ---------------- x -> bf16 cast (once) ----------------
__global__ __launch_bounds__(256) void k_xcast(const float* __restrict__ x,
                                               unsigned short* __restrict__ xb) {
    int i = blockIdx.x * blockDim.x + threadIdx.x;   // over N*TF/8 = 8,000,000
    const float4* x4 = (const float4*)x;
    float4 a = x4[2 * i], b = x4[2 * i + 1];
    uint4 o;
    o.x = pack2(a.x, a.y);
    o.y = pack2(a.z, a.w);
    o.z = pack2(b.x, b.y);
    o.w = pack2(b.z, b.w);
    ((uint4*)xb)[i] = o;
}

// ---------------- degree ----------------
__global__ void k_deg(const int* __restrict__ ei, int* __restrict__ deg) {
    int e = blockIdx.x * blockDim.x + threadIdx.x;
    if (e < E_EDGES) atomicAdd(&deg[ei[E_EDGES + e]], 1);
}

// ---------------- parallel scan: block partials ----------------
__global__ __launch_bounds__(1024) void k_part(const int* __restrict__ deg,
                                               int* __restrict__ part) {
    __shared__ int red[1024];
    int gid = blockIdx.x * 1024 + threadIdx.x;
    red[threadIdx.x] = (gid < N_NODES) ? deg[gid] : 0;
    __syncthreads();
    for (int off = 512; off > 0; off >>= 1) {
        if (threadIdx.x < off) red[threadIdx.x] += red[threadIdx.x + off];
        __syncthreads();
    }
    if (threadIdx.x == 0) part[blockIdx.x] = red[0];
}

__global__ __launch_bounds__(128) void k_scanpart(const int* __restrict__ part,
        int* __restrict__ boff, int* __restrict__ rowptr) {
    __shared__ int buf[128];
    int li = threadIdx.x;
    int v = (li < PBLK) ? part[li] : 0;
    buf[li] = v;
    __syncthreads();
    for (int off = 1; off < 128; off <<= 1) {
        int u = (li >= off) ? buf[li - off] : 0;
        __syncthreads();
        buf[li] += u;
        __syncthreads();
    }
    if (li < PBLK) boff[li] = buf[li] - v;
    if (li == 0) rowptr[N_NODES] = E_EDGES;
}

__global__ __launch_bounds__(1024) void k_rowfill(const int* __restrict__ deg,
        const int* __restrict__ boff, int* __restrict__ rowptr,
        int* __restrict__ cursor, float* __restrict__ inv) {
    __shared__ int buf[1024];
    int li = threadIdx.x;
    int gid = blockIdx.x * 1024 + li;
    int d = (gid < N_NODES) ? deg[gid] : 0;
    buf[li] = d;
    __syncthreads();
    for (int off = 1; off < 1024; off <<= 1) {
        int u = (li >= off) ? buf[li - off] : 0;
        __syncthreads();
        buf[li] += u;
        __syncthreads();
    }
    if (gid < N_NODES) {
        int excl = boff[blockIdx.x] + buf[li] - d;
        rowptr[gid] = excl;
        cursor[gid] = excl;
        inv[gid] = 1.0f / (float)(d > 1 ? d : 1);
    }
}

// ---------------- CSR fill ----------------
__global__ void k_fill(const int* __restrict__ ei, int* __restrict__ cursor,
                       int* __restrict__ csr_src) {
    int e = blockIdx.x * blockDim.x + threadIdx.x;
    if (e < E_EDGES) {
        int dst = ei[E_EDGES + e];
        int pos = atomicAdd(&cursor[dst], 1);
        csr_src[pos] = ei[e];
    }
}

// ---------------- edge-attr aggregation (t-invariant) ----------------
__global__ void k_agge(const int* __restrict__ ei, const float* __restrict__ ea,
                       float* __restrict__ agge) {
    int i = blockIdx.x * blockDim.x + threadIdx.x;   // over E*8
    if (i < E_EDGES * ED_DIM) {
        int e = i >> 3, j = i & 7;
        int dst = ei[E_EDGES + e];
        atomicAdd(&agge[dst * ED_DIM + j], ea[i]);
    }
}

__global__ void k_scale_agge(float* __restrict__ agge, const float* __restrict__ inv,
                             unsigned short* __restrict__ aggeb) {
    int i = blockIdx.x * blockDim.x + threadIdx.x;
    if (i < N_NODES * ED_DIM) {
        float v = agge[i] * inv[i >> 3];
        agge[i] = v;
        aggeb[i] = fbs(v);
    }
}

// ---------------- pack stats weights into MFMA B-frag layout, bf16 ----------------
__global__ void k_wprep(const float* __restrict__ wself, const float* __restrict__ wmsg,
                        unsigned short* __restrict__ wB) {
    int i = blockIdx.x * blockDim.x + threadIdx.x;   // over 5*4096 = 20480
    if (i < 20480) {
        int j = i & 7, q = (i >> 3) & 3, n = (i >> 5) & 127, kt = i >> 12;
        int k = kt * 32 + q * 8 + j;
        float v = 0.f;
        if (k < 64)       v = wself[k * 128 + n];
        else if (k < 136) v = wmsg[(k - 64) * 128 + n];
        wB[i] = fbs(v);
    }
}

// ---------------- pack LSTM weights, gate-permuted MFMA B-frag layout, bf16 ----------------
// col' = hsub*64 + gate*16 + hlo  (wave hsub owns full i,f,g,o for h=hsub*16+hlo)
__global__ void k_wlstm(const float* __restrict__ wih, const float* __restrict__ whh,
                        unsigned short* __restrict__ wL) {
    int i = blockIdx.x * blockDim.x + threadIdx.x;   // over 8*512*32 = 131072
    if (i < 131072) {
        int j8 = i & 7, q = (i >> 3) & 3, np = (i >> 5) & 511, kt = i >> 14;
        int k = kt * 32 + q * 8 + j8;
        int hsub = np >> 6, gate = (np >> 4) & 3, hlo = np & 15;
        int j = gate * 128 + hsub * 16 + hlo;
        float v = (k < 128) ? wih[j * H_DIM + k] : whh[j * H_DIM + (k - 128)];
        wL[i] = fbs(v);
    }
}

// ---------------- per-t CSR gather (bf16): aggxb[n] = inv[n]*sum x_t[src] ----------------
// one wave per node; half-wave per edge, lane = 2 features (uint = 2 bf16)
__global__ __launch_bounds__(256) void k_gather(const unsigned short* __restrict__ xb,
        const int* __restrict__ rowptr, const int* __restrict__ csr_src,
        const float* __restrict__ inv, unsigned short* __restrict__ aggxb, int t) {
    int node = blockIdx.x * 4 + (threadIdx.x >> 6);
    int lane = threadIdx.x & 63;
    int half = lane >> 5, li = lane & 31;
    int beg = rowptr[node], end = rowptr[node + 1];
    const unsigned short* xt = xb + t * F_DIM + 2 * li;
    float a0 = 0.f, a1 = 0.f;
    int e = beg;
    for (; e + 3 < end; e += 4) {
        int s0 = csr_src[e + half], s1 = csr_src[e + 2 + half];
        unsigned int u0 = *(const unsigned int*)&xt[(size_t)s0 * TF];
        unsigned int u1 = *(const unsigned int*)&xt[(size_t)s1 * TF];
        a0 += __uint_as_float(u0 << 16) + __uint_as_float(u1 << 16);
        a1 += __uint_as_float(u0 & 0xffff0000u) + __uint_as_float(u1 & 0xffff0000u);
    }
    if (e + 1 < end) {
        int s = csr_src[e + half];
        unsigned int u = *(const unsigned int*)&xt[(size_t)s * TF];
        a0 += __uint_as_float(u << 16);
        a1 += __uint_as_float(u & 0xffff0000u);
        e += 2;
    }
    if (half == 0 && e < end) {
        int s = csr_src[e];
        unsigned int u = *(const unsigned int*)&xt[(size_t)s * TF];
        a0 += __uint_as_float(u << 16);
        a1 += __uint_as_float(u & 0xffff0000u);
    }
    a0 += __shfl_xor(a0, 32, 64);
    a1 += __shfl_xor(a1, 32, 64);
    if (lane < 32) {
        float iv = inv[node];
        *(unsigned int*)&aggxb[node * F_DIM + 2 * li] = pack2(a0 * iv, a1 * iv);
    }
}

// ---------------- BN stats via bf16 MFMA: sum & sumsq of (xin @ W) ----------------
__global__ __launch_bounds__(256) void k_stats(const unsigned short* __restrict__ xb,
        const unsigned short* __restrict__ aggxb, const unsigned short* __restrict__ aggeb,
        const unsigned short* __restrict__ wB, float* __restrict__ sums, int t) {
    __shared__ __align__(16) unsigned short s_xa[32 * XROW];
    int tid  = threadIdx.x;
    int row0 = blockIdx.x * 32;
    // stage 32 rows x 160 (pad-zeroed) bf16 — pure uint4 copies, no conversion
    for (int i = tid; i < 32 * 20; i += 256) {
        int r = i / 20, q = i - r * 20;
        int n = row0 + r;
        uint4 v = make_uint4(0, 0, 0, 0);
        if (q < 8)        v = *(const uint4*)&xb[(size_t)n * TF + t * F_DIM + q * 8];
        else if (q < 16)  v = *(const uint4*)&aggxb[n * F_DIM + (q - 8) * 8];
        else if (q == 16) v = *(const uint4*)&aggeb[n * ED_DIM];
        *(uint4*)&s_xa[r * XROW + q * 8] = v;
    }
    __syncthreads();

    int wave = tid >> 6, lane = tid & 63;
    int q = lane >> 4, m = lane & 15;
    int n0 = wave * 32;
    f32x4 a00 = {0.f,0.f,0.f,0.f}, a01 = a00, a10 = a00, a11 = a00;
    #pragma unroll
    for (int kt = 0; kt < 5; kt++) {
        short8 af0 = *(const short8*)&s_xa[m * XROW + kt * 32 + q * 8];
        short8 af1 = *(const short8*)&s_xa[(16 + m) * XROW + kt * 32 + q * 8];
        short8 bf0 = *(const short8*)&wB[kt * 4096 + (n0 + m) * 32 + q * 8];
        short8 bf1 = *(const short8*)&wB[kt * 4096 + (n0 + 16 + m) * 32 + q * 8];
        a00 = __builtin_amdgcn_mfma_f32_16x16x32_bf16(af0, bf0, a00, 0, 0, 0);
        a10 = __builtin_amdgcn_mfma_f32_16x16x32_bf16(af1, bf0, a10, 0, 0, 0);
        a01 = __builtin_amdgcn_mfma_f32_16x16x32_bf16(af0, bf1, a01, 0, 0, 0);
        a11 = __builtin_amdgcn_mfma_f32_16x16x32_bf16(af1, bf1, a11, 0, 0, 0);
    }
    #pragma unroll
    for (int ct = 0; ct < 2; ct++) {
        float cs = 0.f, cq = 0.f;
        #pragma unroll
        for (int g = 0; g < 4; g++) {
            float v0 = (ct == 0) ? a00[g] : a01[g];
            float v1 = (ct == 0) ? a10[g] : a11[g];
            cs += v0 + v1;
            cq += v0 * v0 + v1 * v1;
        }
        cs += __shfl_xor(cs, 16, 64); cq += __shfl_xor(cq, 16, 64);
        cs += __shfl_xor(cs, 32, 64); cq += __shfl_xor(cq, 32, 64);
        if (lane < 16) {
            int col = n0 + ct * 16 + m;
            atomicAdd(&sums[col], cs);
            atomicAdd(&sums[128 + col], cq);
        }
    }
}

// ---------------- focal rows: hseqb[t,b,:] = bf16(relu(BN(xin[ptr[b]] @ W))) ----------------
__global__ __launch_bounds__(128) void k_focal(const float* __restrict__ x,
        const unsigned short* __restrict__ aggxb, const float* __restrict__ agge,
        const float* __restrict__ wself, const float* __restrict__ wmsg,
        const float* __restrict__ sums, const float* __restrict__ gamma,
        const float* __restrict__ beta, const int* __restrict__ ptr,
        unsigned short* __restrict__ hseqb, int t) {
    __shared__ float s_xin[K_IN];
    int b   = blockIdx.x;
    int n   = ptr[b];
    int tid = threadIdx.x;
    if (tid < K_IN - 64) {
        int k = 64 + tid;
        s_xin[k] = (k < 128) ? bs2f(aggxb[n * F_DIM + (k - 64)])
                             : agge[n * ED_DIM + (k - 128)];
    }
    {
        int k = tid & 63;
        s_xin[k] = x[(size_t)n * TF + t * F_DIM + k];
    }
    __syncthreads();
    int h = tid;
    float acc = 0.f;
    #pragma unroll 8
    for (int k = 0; k < F_DIM; k++) acc += s_xin[k] * wself[k * H_DIM + h];
    #pragma unroll 8
    for (int k = 0; k < 72; k++)    acc += s_xin[F_DIM + k] * wmsg[k * H_DIM + h];
    float mean = sums[h] * (1.0f / N_NODES);
    float var  = sums[H_DIM + h] * (1.0f / N_NODES) - mean * mean;
    var = fmaxf(var, 0.f);
    float istd = 1.0f / sqrtf(var + 1e-5f);
    float sc = gamma[h] * istd;
    float sh = beta[h] - mean * sc;
    float v = fmaxf(acc * sc + sh, 0.f);
    hseqb[(size_t)(t * B_BATCH + b) * H_DIM + h] = fbs(v);
}

// ---------------- persistent MFMA LSTM: all 10 steps in one kernel ----------------
// 32 blocks x 512 thr; block owns 64 rows; wave owns 64 gate-cols (full i,f,g,o
// for 16 h-dims) -> pointwise is pure register math; c lives in registers.
__global__ __launch_bounds__(512) void k_lstm_all(const unsigned short* __restrict__ hseqb,
        const unsigned short* __restrict__ wL, const float* __restrict__ bih,
        const float* __restrict__ bhh, float* __restrict__ hn) {
    __shared__ __align__(16) unsigned short s_hin[64 * H_DIM];
    __shared__ __align__(16) unsigned short s_h[64 * H_DIM];
    int tid = threadIdx.x, wave = tid >> 6, lane = tid & 63;
    int q = lane >> 4, hlo = lane & 15;
    int row0 = blockIdx.x * 64;
    for (int i = tid; i < 64 * H_DIM / 8; i += 512)
        ((uint4*)s_h)[i] = make_uint4(0, 0, 0, 0);
    float c[4][4];
    #pragma unroll
    for (int m = 0; m < 4; m++)
        #pragma unroll
        for (int r = 0; r < 4; r++) c[m][r] = 0.f;
    float bias[4];
    #pragma unroll
    for (int nt = 0; nt < 4; nt++) {
        int j = nt * 128 + wave * 16 + hlo;
        bias[nt] = bih[j] + bhh[j];
    }
    for (int t = 0; t < T_STEPS; t++) {
        const uint4* src = (const uint4*)(hseqb + (size_t)(t * B_BATCH + row0) * H_DIM);
        for (int i = tid; i < 64 * H_DIM / 8; i += 512) ((uint4*)s_hin)[i] = src[i];
        __syncthreads();   // s_hin staged; prev-iter s_h writes visible
        f32x4 acc[4][4];
        #pragma unroll
        for (int m = 0; m < 4; m++)
            #pragma unroll
            for (int nt = 0; nt < 4; nt++) acc[m][nt] = (f32x4){0.f,0.f,0.f,0.f};
        #pragma unroll
        for (int kt = 0; kt < 8; kt++) {
            const unsigned short* abase = (kt < 4) ? s_hin : s_h;
            int ko = (kt & 3) * 32 + q * 8;
            short8 am[4];
            #pragma unroll
            for (int m = 0; m < 4; m++)
                am[m] = *(const short8*)&abase[(m * 16 + hlo) * H_DIM + ko];
            #pragma unroll
            for (int nt = 0; nt < 4; nt++) {
                short8 bf = *(const short8*)&wL[((kt * 512) + (wave * 64 + nt * 16 + hlo)) * 32 + q * 8];
                #pragma unroll
                for (int m = 0; m < 4; m++)
                    acc[m][nt] = __builtin_amdgcn_mfma_f32_16x16x32_bf16(am[m], bf, acc[m][nt], 0, 0, 0);
            }
        }
        __syncthreads();   // all s_h reads done before overwrite
        #pragma unroll
        for (int m = 0; m < 4; m++) {
            #pragma unroll
            for (int r = 0; r < 4; r++) {
                float gi = acc[m][0][r] + bias[0];
                float gf = acc[m][1][r] + bias[1];
                float gg = acc[m][2][r] + bias[2];
                float go = acc[m][3][r] + bias[3];
                float si = 1.f / (1.f + expf(-gi));
                float sf = 1.f / (1.f + expf(-gf));
                float so = 1.f / (1.f + expf(-go));
                float tg = tanhf(gg);
                float cn = sf * c[m][r] + si * tg;
                c[m][r] = cn;
                float hv = so * tanhf(cn);
                int row = m * 16 + q * 4 + r;
                s_h[row * H_DIM + wave * 16 + hlo] = fbs(hv);
                if (t == T_STEPS - 1)
                    hn[(size_t)(row0 + row) * H_DIM + wave * 16 + hlo] = hv;
            }
        }
    }
}

// ---------------- classifier ----------------
__global__ void k_cls(const float* __restrict__ h, const float* __restrict__ wcls,
                      const float* __restrict__ bcls, float* __restrict__ out) {
    int i = blockIdx.x * blockDim.x + threadIdx.x;
    if (i < B_BATCH * C_CLS) {
        int b = i >> 1, cc = i & 1;
        float acc = bcls[cc];
        for (int k = 0; k < H_DIM; k++) acc += h[b * H_DIM + k] * wcls[k * C_CLS + cc];
        out[i] = acc;
    }
}

extern "C" void kernel_launch(void* const* d_in, const int* in_sizes, int n_in,
                              void* d_out, int out_size, void* d_ws, size_t ws_size,
                              hipStream_t stream) {
    const float* x     = (const float*)d_in[0];
    const int*   ei    = (const int*)d_in[1];
    const float* ea    = (const float*)d_in[2];
    const int*   ptr   = (const int*)d_in[3];
    const float* wmsg  = (const float*)d_in[4];
    const float* wself = (const float*)d_in[6];
    const float* gamma = (const float*)d_in[8];
    const float* beta  = (const float*)d_in[9];
    const float* wih   = (const float*)d_in[10];
    const float* whh   = (const float*)d_in[11];
    const float* bih   = (const float*)d_in[12];
    const float* bhh   = (const float*)d_in[13];
    const float* wcls  = (const float*)d_in[14];
    const float* bcls  = (const float*)d_in[15];
    float* out = (float*)d_out;

    float* ws = (float*)d_ws;
    int*            deg    = (int*)(ws + WS_DEG);
    int*            rowptr = (int*)(ws + WS_ROWPTR);
    int*            cursor = (int*)(ws + WS_CURSOR);
    float*          inv    = ws + WS_INV;
    float*          agge   = ws + WS_AGGE;
    float*          sums   = ws + WS_SUMS;
    int*            csrs   = (int*)(ws + WS_CSRSRC);
    unsigned short* aggxb  = (unsigned short*)(ws + WS_AGGXB);
    unsigned short* aggeb  = (unsigned short*)(ws + WS_AGGEB);
    unsigned short* hseqb  = (unsigned short*)(ws + WS_HSEQB);
    float*          hn     = ws + WS_HN;
    unsigned short* wB     = (unsigned short*)(ws + WS_WB);
    unsigned short* wL     = (unsigned short*)(ws + WS_WL);
    int*            part   = (int*)(ws + WS_PART);
    int*            boff   = (int*)(ws + WS_BOFF);
    unsigned short* xb     = (unsigned short*)(ws + WS_XB);

    hipMemsetAsync(ws, 0, (size_t)WS_ZEND * 4, stream);

    k_xcast<<<31250, 256, 0, stream>>>(x, xb);
    k_deg<<<(E_EDGES + 255) / 256, 256, 0, stream>>>(ei, deg);
    k_part<<<PBLK, 1024, 0, stream>>>(deg, part);
    k_scanpart<<<1, 128, 0, stream>>>(part, boff, rowptr);
    k_rowfill<<<PBLK, 1024, 0, stream>>>(deg, boff, rowptr, cursor, inv);
    k_agge<<<(E_EDGES * ED_DIM + 255) / 256, 256, 0, stream>>>(ei, ea, agge);
    k_scale_agge<<<(N_NODES * ED_DIM + 255) / 256, 256, 0, stream>>>(agge, inv, aggeb);
    k_fill<<<(E_EDGES + 255) / 256, 256, 0, stream>>>(ei, cursor, csrs);
    k_wprep<<<80, 256, 0, stream>>>(wself, wmsg, wB);
    k_wlstm<<<512, 256, 0, stream>>>(wih, whh, wL);

    for (int t = 0; t < T_STEPS; t++) {
        float* sums_t = sums + t * 256;
        k_gather<<<N_NODES / 4, 256, 0, stream>>>(xb, rowptr, csrs, inv, aggxb, t);
        k_stats<<<N_NODES / 32, 256, 0, stream>>>(xb, aggxb, aggeb, wB, sums_t, t);
        k_focal<<<B_BATCH, 128, 0, stream>>>(x, aggxb, agge, wself, wmsg, sums_t,
                                             gamma, beta, ptr, hseqb, t);
    }
    k_lstm_all<<<B_BATCH / 64, 512, 0, stream>>>(hseqb, wL, bih, bhh, hn);
    k_cls<<<(B_BATCH * C_CLS + 255) / 256, 256, 0, stream>>>(hn, wcls, bcls, out);
}